// Round 11
// baseline (433.756 us; speedup 1.0000x reference)
//
#include <hip/hip_runtime.h>
#include <math.h>

namespace {

constexpr int TT  = 192;
constexpr int INp = 24;
constexpr int Kk  = 20;
constexpr int BB  = 8;            // batch rows per block
constexpr int NTHR = 512;         // 8 waves: A=0..3 (L0), B=4..7 (L1)

constexpr int XSTR = 2308;        // xpk row stride (uints)
constexpr int HP   = 36;          // hpk row stride (uints): 32 data + 4 zero pad
constexpr int GW   = 68;          // gscr row stride (floats)

// workspace layout (bytes)
constexpr int WSA_U = 256 * 48;
constexpr int WSB_U = 256 * 64;
constexpr int WP_U  = 21 * 64;
constexpr int WTOT  = WSA_U + WSB_U + WP_U;
constexpr size_t OFF_WSB  = 49152;
constexpr size_t OFF_WP   = 114688;
constexpr size_t OFF_PART = 120832;
constexpr size_t OFF_HIST = 131072;
constexpr size_t ROW_BYTES = (size_t)TT * 64 * 4;

using short8 = __attribute__((ext_vector_type(8))) short;
using f32x4  = __attribute__((ext_vector_type(4))) float;

__device__ __forceinline__ float sigmoidf_(float x) {
  return 1.0f / (1.0f + __expf(-x));
}
__device__ __forceinline__ float tanhf_(float x) {
  return 2.0f / (1.0f + __expf(-2.0f * x)) - 1.0f;
}
__device__ __forceinline__ float softplusf_(float x) {
  return fmaxf(x, 0.0f) + log1pf(__expf(-fabsf(x)));
}
__device__ __forceinline__ unsigned cvt_pk_bf16(float a, float b) {
  unsigned r;
  asm("v_cvt_pk_bf16_f32 %0, %1, %2" : "=v"(r) : "v"(a), "v"(b));
  return r;
}
__device__ __forceinline__ unsigned bf16rne(float x) {
  unsigned u = __float_as_uint(x);
  return (u + 0x7FFFu + ((u >> 16) & 1u)) >> 16;
}
__device__ __forceinline__ short8 as_bf(uint4 u) {
  short8 s; __builtin_memcpy(&s, &u, 16); return s;
}
#define DOT2(acc, wv, vv) \
  asm("v_dot2_f32_bf16 %0, %1, %2, %0" : "+v"(acc) : "v"(wv), "v"(vv))

#define WAVE_LDS_FENCE()                                  \
  do {                                                    \
    asm volatile("s_waitcnt lgkmcnt(0)" ::: "memory");    \
    __builtin_amdgcn_sched_barrier(0);                    \
  } while (0)

// block barrier WITHOUT vmcnt drain (hist stores are fire-and-forget)
#define BLOCK_BARRIER_LGKM()                              \
  do {                                                    \
    __builtin_amdgcn_sched_barrier(0);                    \
    asm volatile("s_waitcnt lgkmcnt(0)" ::: "memory");    \
    __builtin_amdgcn_s_barrier();                         \
    __builtin_amdgcn_sched_barrier(0);                    \
  } while (0)

// ---- weight prep: bf16-pack, GATE-INTERLEAVED cols (col g = feat*4+q) ----
__global__ void wconv_kernel(const float* __restrict__ w_ih0,
                             const float* __restrict__ w_hh0,
                             const float* __restrict__ w_ih1,
                             const float* __restrict__ w_hh1,
                             const float* __restrict__ w_b0,
                             const float* __restrict__ w_g,
                             unsigned* __restrict__ wsA,
                             unsigned* __restrict__ wsB,
                             unsigned* __restrict__ wp) {
  int i = (int)(blockIdx.x * 256 + threadIdx.x);
  if (i >= WTOT) return;
  float lo = 0.f, hi = 0.f;
  if (i < WSA_U) {
    int g = i / 48, j = i % 48;
    int orig = (g & 3) * 64 + (g >> 2);
    if (j < 12)      { lo = w_ih0[orig * 24 + 2 * j]; hi = w_ih0[orig * 24 + 2 * j + 1]; }
    else if (j < 44) { lo = w_hh0[orig * 64 + 2 * (j - 12)]; hi = w_hh0[orig * 64 + 2 * (j - 12) + 1]; }
    wsA[i] = bf16rne(lo) | (bf16rne(hi) << 16);
  } else if (i < WSA_U + WSB_U) {
    int i2 = i - WSA_U;
    int g = i2 / 64, j = i2 % 64;
    int orig = (g & 3) * 64 + (g >> 2);
    if (j < 32) { lo = w_ih1[orig * 64 + 2 * j]; hi = w_ih1[orig * 64 + 2 * j + 1]; }
    else        { lo = w_hh1[orig * 64 + 2 * (j - 32)]; hi = w_hh1[orig * 64 + 2 * (j - 32) + 1]; }
    wsB[i2] = bf16rne(lo) | (bf16rne(hi) << 16);
  } else {
    int i3 = i - WSA_U - WSB_U;
    int o = i3 >> 6, j = i3 & 63;
    const float* row = (o == 0) ? w_b0 : (w_g + (size_t)(o - 1) * 128);
    if (j < 32) { lo = row[4 * j];            hi = row[4 * j + 2]; }
    else        { lo = row[4 * (j - 32) + 1]; hi = row[4 * (j - 32) + 3]; }
    wp[i3] = bf16rne(lo) | (bf16rne(hi) << 16);
  }
}

// ======== kernel 1: layer-pipelined LSTM — waves 0-3: L0(t=i), waves 4-7:
//          L1(t=i-1) concurrently; 1 barrier per iteration ========
__global__ __launch_bounds__(NTHR, 1) void lstm_kernel(
    const float* __restrict__ train,
    const float* __restrict__ b_ih0, const float* __restrict__ b_hh0,
    const float* __restrict__ b_ih1, const float* __restrict__ b_hh1,
    const unsigned* __restrict__ wsA,  // [256][48] interleaved
    const unsigned* __restrict__ wsB,  // [256][64] interleaved
    unsigned* __restrict__ hist,       // [chunk_rows][192][64]
    int rb)
{
  __shared__ __align__(16) unsigned xpk_l[BB][XSTR];
  __shared__ __align__(16) unsigned hpk0_l[2][BB][HP];
  __shared__ __align__(16) unsigned hpk1_l[2][BB][HP];
  __shared__ __align__(16) float gscr_l[8][BB][GW];  // per-wave 64-col scratch

  const int tid   = (int)threadIdx.x;
  const int lane  = tid & 63;
  const int w     = tid >> 6;          // wave
  const bool isA  = (w < 4);
  const int wg    = w & 3;             // index within group
  const int l15   = lane & 15;
  const int grp   = lane >> 4;         // MFMA k-group 0..3
  const int row_a = lane & 7;          // A-frag source row
  const int crow  = lane & 7;          // cell: batch row
  const int cfl   = lane >> 3;         // cell: feat-pair 0..7
  const int fA    = wg * 16 + cfl * 2; // cell: first feature
  const int r0g   = rb + (int)blockIdx.x * BB;

  // ---- stage packed x once ----
  for (int i = tid; i < BB * TT * 12; i += NTHR) {
    int r = i / (TT * 12), rem = i % (TT * 12);
    int t = rem / 12, u = rem % 12;
    const float* p = train + ((size_t)(r0g + r) * TT + t) * INp + 2 * u;
    float2 v = *(const float2*)p;
    xpk_l[r][t * 12 + u] = cvt_pk_bf16(v.x, v.y);
  }
  for (int i = tid; i < 2 * BB * HP; i += NTHR) {
    (&hpk0_l[0][0][0])[i] = 0u;
    (&hpk1_l[0][0][0])[i] = 0u;
  }

  // ---- persistent weight fragments: A: [4 tiles][3], B: [4 tiles][4] ----
  uint4 wf[4][4];
#pragma unroll
  for (int n = 0; n < 4; ++n) {
    const int gcol = wg * 64 + n * 16 + l15;
    if (isA) {
      const unsigned* pa = wsA + (size_t)gcol * 48 + grp * 4;
      wf[n][0] = *(const uint4*)(pa);
      wf[n][1] = *(const uint4*)(pa + 16);
      wf[n][2] = *(const uint4*)(pa + 32);
    } else {
      const unsigned* pb = wsB + (size_t)gcol * 64 + grp * 4;
#pragma unroll
      for (int c = 0; c < 4; ++c) wf[n][c] = *(const uint4*)(pb + c * 16);
    }
  }

  // ---- cell biases for feats fA, fA+1 (layer by group) ----
  const float* bi = isA ? b_ih0 : b_ih1;
  const float* bh = isA ? b_hh0 : b_hh1;
  float bqa[4], bqb[4];
#pragma unroll
  for (int q = 0; q < 4; ++q) {
    bqa[q] = bi[q * 64 + fA]     + bh[q * 64 + fA];
    bqb[q] = bi[q * 64 + fA + 1] + bh[q * 64 + fA + 1];
  }
  float ca = 0.0f, cb = 0.0f;

  unsigned* histp = hist + (size_t)((size_t)blockIdx.x * BB + crow) * TT * 64;
  const int jj = wg * 8 + cfl;        // packed h index 0..31
  // gscr store split: lanes<32 tiles 0-1, lanes>=32 tiles 2-3 (C rows 8-15 dup rows 0-7)
  const int nbase = (lane >> 5) * 2;
  const int rbse  = ((lane >> 4) & 1) * 4;

  __syncthreads();

  for (int i = 0; i <= TT; ++i) {
    const int wp_ = i & 1, rp_ = wp_ ^ 1;   // rp_ = (i-1)&1

    if (isA) {
      if (i < TT) {
        // ---- G0: L0 gates for t=i (reads x(i), h0(i-1)=hpk0[rp_]) ----
        const unsigned* p0 = (grp < 3) ? &xpk_l[row_a][i * 12 + grp * 4]
                                       : &hpk0_l[rp_][row_a][0];
        short8 A0 = as_bf(*(const uint4*)p0);
        short8 A1 = as_bf(*(const uint4*)&hpk0_l[rp_][row_a][4 + grp * 4]);
        short8 A2 = as_bf(*(const uint4*)&hpk0_l[rp_][row_a][20 + grp * 4]);
        f32x4 acc[4];
#pragma unroll
        for (int n = 0; n < 4; ++n) {
          f32x4 z = {0.f, 0.f, 0.f, 0.f};
          acc[n] = __builtin_amdgcn_mfma_f32_16x16x32_bf16(A0, as_bf(wf[n][0]), z, 0, 0, 0);
        }
#pragma unroll
        for (int n = 0; n < 4; ++n)
          acc[n] = __builtin_amdgcn_mfma_f32_16x16x32_bf16(A1, as_bf(wf[n][1]), acc[n], 0, 0, 0);
#pragma unroll
        for (int n = 0; n < 4; ++n)
          acc[n] = __builtin_amdgcn_mfma_f32_16x16x32_bf16(A2, as_bf(wf[n][2]), acc[n], 0, 0, 0);
#pragma unroll
        for (int n = 0; n < 2; ++n)
#pragma unroll
          for (int r = 0; r < 4; ++r)
            gscr_l[w][rbse + r][(nbase + n) * 16 + l15] = acc[nbase + n][r];
        WAVE_LDS_FENCE();
        // ---- cell L0: lane owns (crow, fA) and (crow, fA+1) ----
        float4 gA = *(const float4*)&gscr_l[w][crow][cfl * 8];
        float4 gB = *(const float4*)&gscr_l[w][crow][cfl * 8 + 4];
        float cnA = sigmoidf_(gA.y + bqa[1]) * ca +
                    sigmoidf_(gA.x + bqa[0]) * tanhf_(gA.z + bqa[2]);
        ca = cnA;
        float hA = sigmoidf_(gA.w + bqa[3]) * tanhf_(cnA);
        float cnB = sigmoidf_(gB.y + bqb[1]) * cb +
                    sigmoidf_(gB.x + bqb[0]) * tanhf_(gB.z + bqb[2]);
        cb = cnB;
        float hB = sigmoidf_(gB.w + bqb[3]) * tanhf_(cnB);
        unsigned pk = cvt_pk_bf16(hA, hB);
        hpk0_l[wp_][crow][jj] = pk;
        histp[(size_t)i * 64 + jj] = pk;
      }
    } else {
      if (i >= 1) {
        // ---- G1: L1 gates for t=i-1 (reads h0(i-1)=hpk0[rp_], h1(i-2)=hpk1[wp_]) ----
        short8 B0 = as_bf(*(const uint4*)&hpk0_l[rp_][row_a][grp * 4]);
        short8 B1 = as_bf(*(const uint4*)&hpk0_l[rp_][row_a][16 + grp * 4]);
        short8 B2 = as_bf(*(const uint4*)&hpk1_l[wp_][row_a][grp * 4]);
        short8 B3 = as_bf(*(const uint4*)&hpk1_l[wp_][row_a][16 + grp * 4]);
        f32x4 acc[4];
#pragma unroll
        for (int n = 0; n < 4; ++n) {
          f32x4 z = {0.f, 0.f, 0.f, 0.f};
          acc[n] = __builtin_amdgcn_mfma_f32_16x16x32_bf16(B0, as_bf(wf[n][0]), z, 0, 0, 0);
        }
#pragma unroll
        for (int n = 0; n < 4; ++n)
          acc[n] = __builtin_amdgcn_mfma_f32_16x16x32_bf16(B1, as_bf(wf[n][1]), acc[n], 0, 0, 0);
#pragma unroll
        for (int n = 0; n < 4; ++n)
          acc[n] = __builtin_amdgcn_mfma_f32_16x16x32_bf16(B2, as_bf(wf[n][2]), acc[n], 0, 0, 0);
#pragma unroll
        for (int n = 0; n < 4; ++n)
          acc[n] = __builtin_amdgcn_mfma_f32_16x16x32_bf16(B3, as_bf(wf[n][3]), acc[n], 0, 0, 0);
#pragma unroll
        for (int n = 0; n < 2; ++n)
#pragma unroll
          for (int r = 0; r < 4; ++r)
            gscr_l[w][rbse + r][(nbase + n) * 16 + l15] = acc[nbase + n][r];
        WAVE_LDS_FENCE();
        // ---- cell L1 ----
        float4 gA = *(const float4*)&gscr_l[w][crow][cfl * 8];
        float4 gB = *(const float4*)&gscr_l[w][crow][cfl * 8 + 4];
        float cnA = sigmoidf_(gA.y + bqa[1]) * ca +
                    sigmoidf_(gA.x + bqa[0]) * tanhf_(gA.z + bqa[2]);
        ca = cnA;
        float hA = sigmoidf_(gA.w + bqa[3]) * tanhf_(cnA);
        float cnB = sigmoidf_(gB.y + bqb[1]) * cb +
                    sigmoidf_(gB.x + bqb[0]) * tanhf_(gB.z + bqb[2]);
        cb = cnB;
        float hB = sigmoidf_(gB.w + bqb[3]) * tanhf_(cnB);
        unsigned pk = cvt_pk_bf16(hA, hB);
        hpk1_l[rp_][crow][jj] = pk;   // buffer (i-1)&1
        histp[(size_t)(i - 1) * 64 + 32 + jj] = pk;
      }
    }
    BLOCK_BARRIER_LGKM();  // single barrier per iteration
  }
}

// ======== kernel 2: proj + softplus + CRPS, one lane per (b,t) ========
__global__ __launch_bounds__(192, 2) void crps_kernel(
    const unsigned* __restrict__ hist,
    const float* __restrict__ labels,
    const unsigned* __restrict__ wp,
    const float* __restrict__ bb_b0,
    const float* __restrict__ b_g,
    float* __restrict__ partials,
    int rb)
{
  __shared__ unsigned wp_l[21][64];
  __shared__ float pb_l[21];
  __shared__ float rw_l[3];

  const int tid = (int)threadIdx.x;       // == t
  const int bloc = (int)blockIdx.x;
  const int bglob = rb + bloc;
  const float sig = 1.0f / (float)Kk;

  for (int i = tid; i < 21 * 64; i += 192) wp_l[i >> 6][i & 63] = wp[i];
  if (tid < 21) pb_l[tid] = (tid == 0) ? bb_b0[0] : b_g[tid - 1];
  __syncthreads();

  uint4 hh[16];
  const uint4* hp4 = (const uint4*)(hist + ((size_t)bloc * TT + tid) * 64);
#pragma unroll
  for (int c = 0; c < 16; ++c) hh[c] = hp4[c];
  const float y = labels[(size_t)bglob * TT + tid];

  float bg[21];
#pragma unroll
  for (int o = 0; o < 21; ++o) {
    float lin = pb_l[o];
#pragma unroll
    for (int c = 0; c < 16; ++c) {
      uint4 wv = *(const uint4*)&wp_l[o][c * 4];
      DOT2(lin, wv.x, hh[c].x);
      DOT2(lin, wv.y, hh[c].y);
      DOT2(lin, wv.z, hh[c].z);
      DOT2(lin, wv.w, hh[c].w);
    }
    bg[o] = softplusf_(lin);
  }

  float braw[Kk], bj[Kk], ksi[Kk];
  {
    float kv = 0.0f;
#pragma unroll
    for (int l = 0; l < Kk; ++l) { ksi[l] = kv; kv += sig; }
  }
#pragma unroll
  for (int l = 0; l < Kk; ++l) {
    float bp = (l == 0) ? bg[0] : bg[l];
    braw[l] = (bg[l + 1] - bp) / (2.0f * sig);
  }
#pragma unroll
  for (int l = 0; l < Kk; ++l)
    bj[l] = braw[l] - ((l == 0) ? 0.0f : braw[l - 1]);
  {
    float st = 0.0f;
#pragma unroll
    for (int l = 0; l < Kk - 1; ++l) st += bj[l];
    bj[Kk - 1] = bg[Kk] - st;
  }

  float A = 0.f, tB = 0.f, tC = 0.f, c3a = 0.f;
  float ab[Kk];
  float ad = 3.4e38f, kpick = 0.f;
#pragma unroll
  for (int i = 0; i < Kk; ++i) {
    float kn = bg[0] * ksi[i];
#pragma unroll
    for (int j = 0; j < Kk; ++j) {
      if (j < i) {
        float d = ksi[i] - ksi[j];
        kn = fmaf(bj[j] * d, d, kn);
      }
    }
    float diff = y - kn;
    float abv = (diff > 0.0f) ? bj[i] : 0.0f;
    ab[i] = abv;
    A += abv;
    tB = fmaf(abv, ksi[i], tB);
    tC = fmaf(abv * ksi[i], ksi[i], tC);
    float um = 1.0f - ksi[i], um2 = um * um;
    c3a = fmaf(bj[i] * (1.0f / 6.0f), um2 * um2, c3a);
    float adi = fabsf(diff);
    if (adi < ad) { ad = adi; kpick = ksi[i]; }
  }
  float Bq = bg[0] - 2.0f * tB;
  float Cc = -y + tC;
  float disc = Bq * Bq - 4.0f * A * Cc;
  float A_safe = (A != 0.0f) ? A : 1.0f;
  float B_safe = (Bq != 0.0f) ? Bq : 1.0f;
  float quad = (-Bq + sqrtf(fmaxf(disc, 0.0f))) / (2.0f * A_safe);
  float alpha = (A != 0.0f && disc >= 0.0f)
                    ? quad
                    : ((A == 0.0f) ? (-Cc / B_safe) : kpick);
  float c4 = 0.0f;
#pragma unroll
  for (int i = 0; i < Kk; ++i) {
    float d = alpha - ksi[i];
    c4 = fmaf(ab[i] * (2.0f / 3.0f), d * d * d, c4);
  }
  float crps = y * (2.0f * alpha - 1.0f) +
               bg[0] * ((1.0f / 3.0f) - alpha * alpha) + c3a - c4;

  float v = crps;
#pragma unroll
  for (int off = 32; off > 0; off >>= 1) v += __shfl_xor(v, off, 64);
  if ((tid & 63) == 0) rw_l[tid >> 6] = v;
  __syncthreads();
  if (tid == 0) partials[bglob] = rw_l[0] + rw_l[1] + rw_l[2];
}

__global__ void final_reduce_kernel(const float* __restrict__ partials,
                                    float* __restrict__ out) {
  __shared__ float s_l[1024];
  const int tid = (int)threadIdx.x;
  s_l[tid] = partials[tid] + partials[tid + 1024];
  __syncthreads();
  for (int s = 512; s > 0; s >>= 1) {
    if (tid < s) s_l[tid] += s_l[tid + s];
    __syncthreads();
  }
  if (tid == 0) out[0] = s_l[0] * (1.0f / 2048.0f);
}

}  // namespace

extern "C" void kernel_launch(void* const* d_in, const int* in_sizes, int n_in,
                              void* d_out, int out_size, void* d_ws, size_t ws_size,
                              hipStream_t stream) {
  (void)in_sizes; (void)n_in; (void)out_size;
  const float* train  = (const float*)d_in[0];
  const float* labels = (const float*)d_in[1];
  const float* w_ih0  = (const float*)d_in[2];
  const float* w_hh0  = (const float*)d_in[3];
  const float* b_ih0  = (const float*)d_in[4];
  const float* b_hh0  = (const float*)d_in[5];
  const float* w_ih1  = (const float*)d_in[6];
  const float* w_hh1  = (const float*)d_in[7];
  const float* b_ih1  = (const float*)d_in[8];
  const float* b_hh1  = (const float*)d_in[9];
  const float* w_b0   = (const float*)d_in[10];
  const float* bb_b0  = (const float*)d_in[11];
  const float* w_g    = (const float*)d_in[12];
  const float* b_g    = (const float*)d_in[13];

  unsigned* wsA   = (unsigned*)d_ws;
  unsigned* wsB   = (unsigned*)((char*)d_ws + OFF_WSB);
  unsigned* wp    = (unsigned*)((char*)d_ws + OFF_WP);
  float* partials = (float*)((char*)d_ws + OFF_PART);
  unsigned* hist  = (unsigned*)((char*)d_ws + OFF_HIST);

  size_t avail = (ws_size > OFF_HIST) ? (ws_size - OFF_HIST) : 0;
  size_t rows_fit = avail / ROW_BYTES;
  int chunk = (rows_fit >= 2048) ? 2048 : (int)rows_fit;
  chunk &= ~7;
  if (chunk < 8) chunk = 8;

  wconv_kernel<<<dim3((WTOT + 255) / 256), dim3(256), 0, stream>>>(
      w_ih0, w_hh0, w_ih1, w_hh1, w_b0, w_g, wsA, wsB, wp);

  for (int rb = 0; rb < 2048; rb += chunk) {
    int cur = (2048 - rb < chunk) ? (2048 - rb) : chunk;
    lstm_kernel<<<dim3(cur / 8), dim3(NTHR), 0, stream>>>(
        train, b_ih0, b_hh0, b_ih1, b_hh1, wsA, wsB, hist, rb);
    crps_kernel<<<dim3(cur), dim3(192), 0, stream>>>(
        hist, labels, wp, bb_b0, b_g, partials, rb);
  }
  final_reduce_kernel<<<dim3(1), dim3(1024), 0, stream>>>(partials,
                                                          (float*)d_out);
}

// Round 12
// 314.055 us; speedup vs baseline: 1.3811x; 1.3811x over previous
//
#include <hip/hip_runtime.h>
#include <math.h>

namespace {

constexpr int TT  = 192;
constexpr int INp = 24;
constexpr int Kk  = 20;
constexpr int BB  = 8;            // batch rows per block
constexpr int NTHR = 512;         // 8 waves, symmetric (R9 schedule)

constexpr int XSTR = 2308;        // xpk row stride (uints)
constexpr int HP   = 36;          // hpk row stride (uints): 32 data + 4 zero pad
constexpr int GS   = 36;          // gscr row stride (floats; 16B-aligned rows)

// workspace layout (bytes)
constexpr int WSA_U = 256 * 48;
constexpr int WSB_U = 256 * 64;
constexpr int WP_U  = 21 * 64;
constexpr int WTOT  = WSA_U + WSB_U + WP_U;
constexpr size_t OFF_WSB  = 49152;
constexpr size_t OFF_WP   = 114688;
constexpr size_t OFF_PART = 120832;
constexpr size_t OFF_HIST = 131072;
constexpr size_t ROW_BYTES = (size_t)TT * 64 * 4;

using short8 = __attribute__((ext_vector_type(8))) short;
using f32x4  = __attribute__((ext_vector_type(4))) float;

__device__ __forceinline__ float sigmoidf_(float x) {
  return 1.0f / (1.0f + __expf(-x));
}
__device__ __forceinline__ float tanhf_(float x) {
  return 2.0f / (1.0f + __expf(-2.0f * x)) - 1.0f;
}
__device__ __forceinline__ float softplusf_(float x) {
  return fmaxf(x, 0.0f) + log1pf(__expf(-fabsf(x)));
}
__device__ __forceinline__ unsigned cvt_pk_bf16(float a, float b) {
  unsigned r;
  asm("v_cvt_pk_bf16_f32 %0, %1, %2" : "=v"(r) : "v"(a), "v"(b));
  return r;
}
__device__ __forceinline__ unsigned bf16rne(float x) {
  unsigned u = __float_as_uint(x);
  return (u + 0x7FFFu + ((u >> 16) & 1u)) >> 16;
}
__device__ __forceinline__ short8 as_bf(uint4 u) {
  short8 s; __builtin_memcpy(&s, &u, 16); return s;
}
#define DOT2(acc, wv, vv) \
  asm("v_dot2_f32_bf16 %0, %1, %2, %0" : "+v"(acc) : "v"(wv), "v"(vv))

#define WAVE_LDS_FENCE()                                  \
  do {                                                    \
    asm volatile("s_waitcnt lgkmcnt(0)" ::: "memory");    \
    __builtin_amdgcn_sched_barrier(0);                    \
  } while (0)

// block barrier WITHOUT vmcnt drain (hist stores are fire-and-forget)
#define BLOCK_BARRIER_LGKM()                              \
  do {                                                    \
    __builtin_amdgcn_sched_barrier(0);                    \
    asm volatile("s_waitcnt lgkmcnt(0)" ::: "memory");    \
    __builtin_amdgcn_s_barrier();                         \
    __builtin_amdgcn_sched_barrier(0);                    \
  } while (0)

// ---- weight prep: bf16-pack, GATE-INTERLEAVED cols (col g = feat*4+q) ----
__global__ void wconv_kernel(const float* __restrict__ w_ih0,
                             const float* __restrict__ w_hh0,
                             const float* __restrict__ w_ih1,
                             const float* __restrict__ w_hh1,
                             const float* __restrict__ w_b0,
                             const float* __restrict__ w_g,
                             unsigned* __restrict__ wsA,
                             unsigned* __restrict__ wsB,
                             unsigned* __restrict__ wp) {
  int i = (int)(blockIdx.x * 256 + threadIdx.x);
  if (i >= WTOT) return;
  float lo = 0.f, hi = 0.f;
  if (i < WSA_U) {
    int g = i / 48, j = i % 48;
    int orig = (g & 3) * 64 + (g >> 2);
    if (j < 12)      { lo = w_ih0[orig * 24 + 2 * j]; hi = w_ih0[orig * 24 + 2 * j + 1]; }
    else if (j < 44) { lo = w_hh0[orig * 64 + 2 * (j - 12)]; hi = w_hh0[orig * 64 + 2 * (j - 12) + 1]; }
    wsA[i] = bf16rne(lo) | (bf16rne(hi) << 16);
  } else if (i < WSA_U + WSB_U) {
    int i2 = i - WSA_U;
    int g = i2 / 64, j = i2 % 64;
    int orig = (g & 3) * 64 + (g >> 2);
    if (j < 32) { lo = w_ih1[orig * 64 + 2 * j]; hi = w_ih1[orig * 64 + 2 * j + 1]; }
    else        { lo = w_hh1[orig * 64 + 2 * (j - 32)]; hi = w_hh1[orig * 64 + 2 * (j - 32) + 1]; }
    wsB[i2] = bf16rne(lo) | (bf16rne(hi) << 16);
  } else {
    int i3 = i - WSA_U - WSB_U;
    int o = i3 >> 6, j = i3 & 63;
    const float* row = (o == 0) ? w_b0 : (w_g + (size_t)(o - 1) * 128);
    if (j < 32) { lo = row[4 * j];            hi = row[4 * j + 2]; }
    else        { lo = row[4 * (j - 32) + 1]; hi = row[4 * (j - 32) + 3]; }
    wp[i3] = bf16rne(lo) | (bf16rne(hi) << 16);
  }
}

// ======== kernel 1: LSTM, R9 symmetric-wave schedule with MERGED phase:
//          per iter i, every wave computes G1(i) + G0(i+1), then both cells.
//          1 chain segment + 1 barrier per step (R9 had 2 segments). ========
__global__ __launch_bounds__(NTHR, 1) void lstm_kernel(
    const float* __restrict__ train,
    const float* __restrict__ b_ih0, const float* __restrict__ b_hh0,
    const float* __restrict__ b_ih1, const float* __restrict__ b_hh1,
    const unsigned* __restrict__ wsA,  // [256][48] interleaved
    const unsigned* __restrict__ wsB,  // [256][64] interleaved
    unsigned* __restrict__ hist,       // [chunk_rows][192][64]
    int rb)
{
  __shared__ __align__(16) unsigned xpk_l[BB][XSTR];
  __shared__ __align__(16) unsigned hpk0_l[2][BB][HP];
  __shared__ __align__(16) unsigned hpk1_l[2][BB][HP];
  __shared__ __align__(16) float gscrA_l[8][BB][GS];  // L0 gates (t+1)
  __shared__ __align__(16) float gscrB_l[8][BB][GS];  // L1 gates (t)

  const int tid   = (int)threadIdx.x;
  const int lane  = tid & 63;
  const int w     = tid >> 6;      // wave; owns interleaved cols [w*32,+32) both layers
  const int l15   = lane & 15;
  const int grp   = lane >> 4;     // MFMA k-group 0..3
  const int row_a = lane & 7;      // A-frag source row (8-15 dup)
  const int crow  = lane & 7;      // cell: batch row
  const int cfl   = lane >> 3;     // cell: local feature 0..7
  const int feat  = w * 8 + cfl;   // global feature
  const int r0g   = rb + (int)blockIdx.x * BB;

  // ---- stage packed x once ----
  for (int i = tid; i < BB * TT * 12; i += NTHR) {
    int r = i / (TT * 12), rem = i % (TT * 12);
    int t = rem / 12, u = rem % 12;
    const float* p = train + ((size_t)(r0g + r) * TT + t) * INp + 2 * u;
    float2 v = *(const float2*)p;
    xpk_l[r][t * 12 + u] = cvt_pk_bf16(v.x, v.y);
  }
  for (int i = tid; i < 2 * BB * HP; i += NTHR) {
    (&hpk0_l[0][0][0])[i] = 0u;
    (&hpk1_l[0][0][0])[i] = 0u;
  }

  // ---- persistent MFMA weight fragments (28 uints) ----
  uint4 wAf[2][3], wBf[2][4];
#pragma unroll
  for (int n = 0; n < 2; ++n) {
    const int gcol = w * 32 + n * 16 + l15;
    const unsigned* pa = wsA + (size_t)gcol * 48 + grp * 4;
    wAf[n][0] = *(const uint4*)(pa);
    wAf[n][1] = *(const uint4*)(pa + 16);
    wAf[n][2] = *(const uint4*)(pa + 32);
    const unsigned* pb = wsB + (size_t)gcol * 64 + grp * 4;
#pragma unroll
    for (int c = 0; c < 4; ++c) wBf[n][c] = *(const uint4*)(pb + c * 16);
  }

  // ---- cell biases (gate-interleaved: q = i,f,g,o) ----
  float bq0[4], bq1[4];
#pragma unroll
  for (int q = 0; q < 4; ++q) {
    bq0[q] = b_ih0[q * 64 + feat] + b_hh0[q * 64 + feat];
    bq1[q] = b_ih1[q * 64 + feat] + b_hh1[q * 64 + feat];
  }
  float c0 = 0.0f, c1 = 0.0f;

  unsigned* histp = hist + (size_t)((size_t)blockIdx.x * BB + crow) * TT * 64;
  const int j0 = w * 4 + (cfl >> 1);
  const bool writer = ((cfl & 1) == 0);
  const int rbse = (lane >> 4) * 4;   // C-rows for lanes<32

  __syncthreads();

  // ======== prologue: G0(0) + cell0(0) (h0(-1)=0 via zeroed hpk0[1]) ========
  {
    const unsigned* p0 = (grp < 3) ? &xpk_l[row_a][grp * 4]
                                   : &hpk0_l[1][row_a][0];
    short8 A0 = as_bf(*(const uint4*)p0);
    short8 A1 = as_bf(*(const uint4*)&hpk0_l[1][row_a][4 + grp * 4]);
    short8 A2 = as_bf(*(const uint4*)&hpk0_l[1][row_a][20 + grp * 4]);
    f32x4 z = {0.f, 0.f, 0.f, 0.f};
    f32x4 a0 = z, a1 = z;
    a0 = __builtin_amdgcn_mfma_f32_16x16x32_bf16(A0, as_bf(wAf[0][0]), a0, 0, 0, 0);
    a1 = __builtin_amdgcn_mfma_f32_16x16x32_bf16(A0, as_bf(wAf[1][0]), a1, 0, 0, 0);
    a0 = __builtin_amdgcn_mfma_f32_16x16x32_bf16(A1, as_bf(wAf[0][1]), a0, 0, 0, 0);
    a1 = __builtin_amdgcn_mfma_f32_16x16x32_bf16(A1, as_bf(wAf[1][1]), a1, 0, 0, 0);
    a0 = __builtin_amdgcn_mfma_f32_16x16x32_bf16(A2, as_bf(wAf[0][2]), a0, 0, 0, 0);
    a1 = __builtin_amdgcn_mfma_f32_16x16x32_bf16(A2, as_bf(wAf[1][2]), a1, 0, 0, 0);
    if (lane < 32) {
#pragma unroll
      for (int r = 0; r < 4; ++r) {
        gscrA_l[w][rbse + r][l15]      = a0[r];
        gscrA_l[w][rbse + r][l15 + 16] = a1[r];
      }
    }
    WAVE_LDS_FENCE();
    float4 g0v = *(const float4*)&gscrA_l[w][crow][cfl * 4];
    float cn = sigmoidf_(g0v.y + bq0[1]) * c0 +
               sigmoidf_(g0v.x + bq0[0]) * tanhf_(g0v.z + bq0[2]);
    c0 = cn;
    float h0v = sigmoidf_(g0v.w + bq0[3]) * tanhf_(cn);
    float nb = __shfl_xor(h0v, 8, 64);
    if (writer) {
      unsigned pk = cvt_pk_bf16(h0v, nb);
      hpk0_l[0][crow][j0] = pk;
      histp[j0] = pk;
    }
  }
  BLOCK_BARRIER_LGKM();

  // ======== main loop: iter i computes G1(i)+G0(i+1), cells, 1 barrier ====
  for (int i = 0; i < TT - 1; ++i) {
    const int cur = i & 1, nxt = cur ^ 1;

    // ---- merged gate phase: 7 ds_reads, 14 MFMA (4 independent chains) ----
    short8 B0 = as_bf(*(const uint4*)&hpk0_l[cur][row_a][grp * 4]);
    short8 B1 = as_bf(*(const uint4*)&hpk0_l[cur][row_a][16 + grp * 4]);
    short8 B2 = as_bf(*(const uint4*)&hpk1_l[nxt][row_a][grp * 4]);
    short8 B3 = as_bf(*(const uint4*)&hpk1_l[nxt][row_a][16 + grp * 4]);
    const unsigned* p0 = (grp < 3) ? &xpk_l[row_a][(i + 1) * 12 + grp * 4]
                                   : &hpk0_l[cur][row_a][0];
    short8 A0 = as_bf(*(const uint4*)p0);
    short8 A1 = as_bf(*(const uint4*)&hpk0_l[cur][row_a][4 + grp * 4]);
    short8 A2 = as_bf(*(const uint4*)&hpk0_l[cur][row_a][20 + grp * 4]);

    f32x4 z = {0.f, 0.f, 0.f, 0.f};
    f32x4 b0a = z, b1a = z, a0a = z, a1a = z;
    b0a = __builtin_amdgcn_mfma_f32_16x16x32_bf16(B0, as_bf(wBf[0][0]), b0a, 0, 0, 0);
    b1a = __builtin_amdgcn_mfma_f32_16x16x32_bf16(B0, as_bf(wBf[1][0]), b1a, 0, 0, 0);
    a0a = __builtin_amdgcn_mfma_f32_16x16x32_bf16(A0, as_bf(wAf[0][0]), a0a, 0, 0, 0);
    a1a = __builtin_amdgcn_mfma_f32_16x16x32_bf16(A0, as_bf(wAf[1][0]), a1a, 0, 0, 0);
    b0a = __builtin_amdgcn_mfma_f32_16x16x32_bf16(B1, as_bf(wBf[0][1]), b0a, 0, 0, 0);
    b1a = __builtin_amdgcn_mfma_f32_16x16x32_bf16(B1, as_bf(wBf[1][1]), b1a, 0, 0, 0);
    a0a = __builtin_amdgcn_mfma_f32_16x16x32_bf16(A1, as_bf(wAf[0][1]), a0a, 0, 0, 0);
    a1a = __builtin_amdgcn_mfma_f32_16x16x32_bf16(A1, as_bf(wAf[1][1]), a1a, 0, 0, 0);
    b0a = __builtin_amdgcn_mfma_f32_16x16x32_bf16(B2, as_bf(wBf[0][2]), b0a, 0, 0, 0);
    b1a = __builtin_amdgcn_mfma_f32_16x16x32_bf16(B2, as_bf(wBf[1][2]), b1a, 0, 0, 0);
    a0a = __builtin_amdgcn_mfma_f32_16x16x32_bf16(A2, as_bf(wAf[0][2]), a0a, 0, 0, 0);
    a1a = __builtin_amdgcn_mfma_f32_16x16x32_bf16(A2, as_bf(wAf[1][2]), a1a, 0, 0, 0);
    b0a = __builtin_amdgcn_mfma_f32_16x16x32_bf16(B3, as_bf(wBf[0][3]), b0a, 0, 0, 0);
    b1a = __builtin_amdgcn_mfma_f32_16x16x32_bf16(B3, as_bf(wBf[1][3]), b1a, 0, 0, 0);

    if (lane < 32) {
#pragma unroll
      for (int r = 0; r < 4; ++r) {
        gscrB_l[w][rbse + r][l15]      = b0a[r];
        gscrB_l[w][rbse + r][l15 + 16] = b1a[r];
        gscrA_l[w][rbse + r][l15]      = a0a[r];
        gscrA_l[w][rbse + r][l15 + 16] = a1a[r];
      }
    }
    WAVE_LDS_FENCE();

    // ---- cells: cell1(i) and cell0(i+1), independent (ILP) ----
    {
      float4 g1v = *(const float4*)&gscrB_l[w][crow][cfl * 4];
      float4 g0v = *(const float4*)&gscrA_l[w][crow][cfl * 4];
      float cn1 = sigmoidf_(g1v.y + bq1[1]) * c1 +
                  sigmoidf_(g1v.x + bq1[0]) * tanhf_(g1v.z + bq1[2]);
      c1 = cn1;
      float h1v = sigmoidf_(g1v.w + bq1[3]) * tanhf_(cn1);
      float cn0 = sigmoidf_(g0v.y + bq0[1]) * c0 +
                  sigmoidf_(g0v.x + bq0[0]) * tanhf_(g0v.z + bq0[2]);
      c0 = cn0;
      float h0v = sigmoidf_(g0v.w + bq0[3]) * tanhf_(cn0);
      float n1 = __shfl_xor(h1v, 8, 64);
      float n0 = __shfl_xor(h0v, 8, 64);
      if (writer) {
        unsigned pk1 = cvt_pk_bf16(h1v, n1);
        unsigned pk0 = cvt_pk_bf16(h0v, n0);
        hpk1_l[cur][crow][j0] = pk1;
        hpk0_l[nxt][crow][j0] = pk0;
        histp[(size_t)i * 64 + 32 + j0] = pk1;
        histp[(size_t)(i + 1) * 64 + j0] = pk0;
      }
    }
    BLOCK_BARRIER_LGKM();
  }

  // ======== epilogue: G1(TT-1) + cell1(TT-1) ========
  {
    const int cur = (TT - 1) & 1, nxt = cur ^ 1;
    short8 B0 = as_bf(*(const uint4*)&hpk0_l[cur][row_a][grp * 4]);
    short8 B1 = as_bf(*(const uint4*)&hpk0_l[cur][row_a][16 + grp * 4]);
    short8 B2 = as_bf(*(const uint4*)&hpk1_l[nxt][row_a][grp * 4]);
    short8 B3 = as_bf(*(const uint4*)&hpk1_l[nxt][row_a][16 + grp * 4]);
    f32x4 z = {0.f, 0.f, 0.f, 0.f};
    f32x4 b0a = z, b1a = z;
    b0a = __builtin_amdgcn_mfma_f32_16x16x32_bf16(B0, as_bf(wBf[0][0]), b0a, 0, 0, 0);
    b1a = __builtin_amdgcn_mfma_f32_16x16x32_bf16(B0, as_bf(wBf[1][0]), b1a, 0, 0, 0);
    b0a = __builtin_amdgcn_mfma_f32_16x16x32_bf16(B1, as_bf(wBf[0][1]), b0a, 0, 0, 0);
    b1a = __builtin_amdgcn_mfma_f32_16x16x32_bf16(B1, as_bf(wBf[1][1]), b1a, 0, 0, 0);
    b0a = __builtin_amdgcn_mfma_f32_16x16x32_bf16(B2, as_bf(wBf[0][2]), b0a, 0, 0, 0);
    b1a = __builtin_amdgcn_mfma_f32_16x16x32_bf16(B2, as_bf(wBf[1][2]), b1a, 0, 0, 0);
    b0a = __builtin_amdgcn_mfma_f32_16x16x32_bf16(B3, as_bf(wBf[0][3]), b0a, 0, 0, 0);
    b1a = __builtin_amdgcn_mfma_f32_16x16x32_bf16(B3, as_bf(wBf[1][3]), b1a, 0, 0, 0);
    if (lane < 32) {
#pragma unroll
      for (int r = 0; r < 4; ++r) {
        gscrB_l[w][rbse + r][l15]      = b0a[r];
        gscrB_l[w][rbse + r][l15 + 16] = b1a[r];
      }
    }
    WAVE_LDS_FENCE();
    float4 g1v = *(const float4*)&gscrB_l[w][crow][cfl * 4];
    float cn1 = sigmoidf_(g1v.y + bq1[1]) * c1 +
                sigmoidf_(g1v.x + bq1[0]) * tanhf_(g1v.z + bq1[2]);
    float h1v = sigmoidf_(g1v.w + bq1[3]) * tanhf_(cn1);
    float n1 = __shfl_xor(h1v, 8, 64);
    if (writer) {
      histp[(size_t)(TT - 1) * 64 + 32 + j0] = cvt_pk_bf16(h1v, n1);
    }
  }
}

// ======== kernel 2: proj + softplus + CRPS, one lane per (b,t) ========
__global__ __launch_bounds__(192, 2) void crps_kernel(
    const unsigned* __restrict__ hist,
    const float* __restrict__ labels,
    const unsigned* __restrict__ wp,
    const float* __restrict__ bb_b0,
    const float* __restrict__ b_g,
    float* __restrict__ partials,
    int rb)
{
  __shared__ unsigned wp_l[21][64];
  __shared__ float pb_l[21];
  __shared__ float rw_l[3];

  const int tid = (int)threadIdx.x;       // == t
  const int bloc = (int)blockIdx.x;
  const int bglob = rb + bloc;
  const float sig = 1.0f / (float)Kk;

  for (int i = tid; i < 21 * 64; i += 192) wp_l[i >> 6][i & 63] = wp[i];
  if (tid < 21) pb_l[tid] = (tid == 0) ? bb_b0[0] : b_g[tid - 1];
  __syncthreads();

  uint4 hh[16];
  const uint4* hp4 = (const uint4*)(hist + ((size_t)bloc * TT + tid) * 64);
#pragma unroll
  for (int c = 0; c < 16; ++c) hh[c] = hp4[c];
  const float y = labels[(size_t)bglob * TT + tid];

  float bg[21];
#pragma unroll
  for (int o = 0; o < 21; ++o) {
    float lin = pb_l[o];
#pragma unroll
    for (int c = 0; c < 16; ++c) {
      uint4 wv = *(const uint4*)&wp_l[o][c * 4];
      DOT2(lin, wv.x, hh[c].x);
      DOT2(lin, wv.y, hh[c].y);
      DOT2(lin, wv.z, hh[c].z);
      DOT2(lin, wv.w, hh[c].w);
    }
    bg[o] = softplusf_(lin);
  }

  float braw[Kk], bj[Kk], ksi[Kk];
  {
    float kv = 0.0f;
#pragma unroll
    for (int l = 0; l < Kk; ++l) { ksi[l] = kv; kv += sig; }
  }
#pragma unroll
  for (int l = 0; l < Kk; ++l) {
    float bp = (l == 0) ? bg[0] : bg[l];
    braw[l] = (bg[l + 1] - bp) / (2.0f * sig);
  }
#pragma unroll
  for (int l = 0; l < Kk; ++l)
    bj[l] = braw[l] - ((l == 0) ? 0.0f : braw[l - 1]);
  {
    float st = 0.0f;
#pragma unroll
    for (int l = 0; l < Kk - 1; ++l) st += bj[l];
    bj[Kk - 1] = bg[Kk] - st;
  }

  float A = 0.f, tB = 0.f, tC = 0.f, c3a = 0.f;
  float ab[Kk];
  float ad = 3.4e38f, kpick = 0.f;
#pragma unroll
  for (int i = 0; i < Kk; ++i) {
    float kn = bg[0] * ksi[i];
#pragma unroll
    for (int j = 0; j < Kk; ++j) {
      if (j < i) {
        float d = ksi[i] - ksi[j];
        kn = fmaf(bj[j] * d, d, kn);
      }
    }
    float diff = y - kn;
    float abv = (diff > 0.0f) ? bj[i] : 0.0f;
    ab[i] = abv;
    A += abv;
    tB = fmaf(abv, ksi[i], tB);
    tC = fmaf(abv * ksi[i], ksi[i], tC);
    float um = 1.0f - ksi[i], um2 = um * um;
    c3a = fmaf(bj[i] * (1.0f / 6.0f), um2 * um2, c3a);
    float adi = fabsf(diff);
    if (adi < ad) { ad = adi; kpick = ksi[i]; }
  }
  float Bq = bg[0] - 2.0f * tB;
  float Cc = -y + tC;
  float disc = Bq * Bq - 4.0f * A * Cc;
  float A_safe = (A != 0.0f) ? A : 1.0f;
  float B_safe = (Bq != 0.0f) ? Bq : 1.0f;
  float quad = (-Bq + sqrtf(fmaxf(disc, 0.0f))) / (2.0f * A_safe);
  float alpha = (A != 0.0f && disc >= 0.0f)
                    ? quad
                    : ((A == 0.0f) ? (-Cc / B_safe) : kpick);
  float c4 = 0.0f;
#pragma unroll
  for (int i = 0; i < Kk; ++i) {
    float d = alpha - ksi[i];
    c4 = fmaf(ab[i] * (2.0f / 3.0f), d * d * d, c4);
  }
  float crps = y * (2.0f * alpha - 1.0f) +
               bg[0] * ((1.0f / 3.0f) - alpha * alpha) + c3a - c4;

  float v = crps;
#pragma unroll
  for (int off = 32; off > 0; off >>= 1) v += __shfl_xor(v, off, 64);
  if ((tid & 63) == 0) rw_l[tid >> 6] = v;
  __syncthreads();
  if (tid == 0) partials[bglob] = rw_l[0] + rw_l[1] + rw_l[2];
}

__global__ void final_reduce_kernel(const float* __restrict__ partials,
                                    float* __restrict__ out) {
  __shared__ float s_l[1024];
  const int tid = (int)threadIdx.x;
  s_l[tid] = partials[tid] + partials[tid + 1024];
  __syncthreads();
  for (int s = 512; s > 0; s >>= 1) {
    if (tid < s) s_l[tid] += s_l[tid + s];
    __syncthreads();
  }
  if (tid == 0) out[0] = s_l[0] * (1.0f / 2048.0f);
}

}  // namespace

extern "C" void kernel_launch(void* const* d_in, const int* in_sizes, int n_in,
                              void* d_out, int out_size, void* d_ws, size_t ws_size,
                              hipStream_t stream) {
  (void)in_sizes; (void)n_in; (void)out_size;
  const float* train  = (const float*)d_in[0];
  const float* labels = (const float*)d_in[1];
  const float* w_ih0  = (const float*)d_in[2];
  const float* w_hh0  = (const float*)d_in[3];
  const float* b_ih0  = (const float*)d_in[4];
  const float* b_hh0  = (const float*)d_in[5];
  const float* w_ih1  = (const float*)d_in[6];
  const float* w_hh1  = (const float*)d_in[7];
  const float* b_ih1  = (const float*)d_in[8];
  const float* b_hh1  = (const float*)d_in[9];
  const float* w_b0   = (const float*)d_in[10];
  const float* bb_b0  = (const float*)d_in[11];
  const float* w_g    = (const float*)d_in[12];
  const float* b_g    = (const float*)d_in[13];

  unsigned* wsA   = (unsigned*)d_ws;
  unsigned* wsB   = (unsigned*)((char*)d_ws + OFF_WSB);
  unsigned* wp    = (unsigned*)((char*)d_ws + OFF_WP);
  float* partials = (float*)((char*)d_ws + OFF_PART);
  unsigned* hist  = (unsigned*)((char*)d_ws + OFF_HIST);

  size_t avail = (ws_size > OFF_HIST) ? (ws_size - OFF_HIST) : 0;
  size_t rows_fit = avail / ROW_BYTES;
  int chunk = (rows_fit >= 2048) ? 2048 : (int)rows_fit;
  chunk &= ~7;
  if (chunk < 8) chunk = 8;

  wconv_kernel<<<dim3((WTOT + 255) / 256), dim3(256), 0, stream>>>(
      w_ih0, w_hh0, w_ih1, w_hh1, w_b0, w_g, wsA, wsB, wp);

  for (int rb = 0; rb < 2048; rb += chunk) {
    int cur = (2048 - rb < chunk) ? (2048 - rb) : chunk;
    lstm_kernel<<<dim3(cur / 8), dim3(NTHR), 0, stream>>>(
        train, b_ih0, b_hh0, b_ih1, b_hh1, wsA, wsB, hist, rb);
    crps_kernel<<<dim3(cur), dim3(192), 0, stream>>>(
        hist, labels, wp, bb_b0, b_g, partials, rb);
  }
  final_reduce_kernel<<<dim3(1), dim3(1024), 0, stream>>>(partials,
                                                          (float*)d_out);
}